// Round 2
// baseline (335.406 us; speedup 1.0000x reference)
//
#include <hip/hip_runtime.h>
#include <hip/hip_fp16.h>

// FrameConsistencyLoss: mean over (N,64) of (proj_a - proj_b)^2 where
// proj_x[i] = x[i] @ W[ids_x[i]] + b[ids_x[i]], N=2e6, REL_DIM=14, CAN_DIM=64, 4 experts.
//
// R2 strategy: NO LDS, NO barriers. Compute all 4 expert projections per row via
// K=16 MFMA (k0..13 = x, k14 = 1.0 -> bias row of W~, k15 = 0), then per-row
// cndmask-select the (ea, eb) tiles in the C-layout epilogue and accumulate
// sum((pa-pb)^2). A-fragments load straight from global (fixed layout, float2
// 8B-aligned); W~ fragments are register-resident (16 tiles = expert x colgroup).
// A/B share the k-mapping (symmetric), so k-permutation errors cancel exactly;
// C/D mapping col=lane&15, row=quad*4+reg is the m89-verified one.

#define N_ROWS  2000000
#define N_TILES (N_ROWS / 16)   // 125000 exact

typedef _Float16 h4 __attribute__((ext_vector_type(4)));
typedef _Float16 h8 __attribute__((ext_vector_type(8)));
typedef float    f4 __attribute__((ext_vector_type(4)));

#if __has_builtin(__builtin_amdgcn_mfma_f32_16x16x16f16)
#define USE_K16 1
#else
#define USE_K16 0
#endif

__global__ void __launch_bounds__(256)
frame_loss(const float* __restrict__ A, const float* __restrict__ B,
           const int* __restrict__ IDA, const int* __restrict__ IDB,
           const float* __restrict__ W, const float* __restrict__ BIAS,
           float* __restrict__ out)
{
    const int lane = threadIdx.x & 63;
    const int sub  = lane & 15;   // A row within tile / C-D col (W-col sub-index)
    const int quad = lane >> 4;   // k-group for A/B operands; row-group for C/D
    const int wave   = blockIdx.x * (blockDim.x >> 6) + (threadIdx.x >> 6);
    const int nwaves = gridDim.x * (blockDim.x >> 6);

    // ---- Register-resident W~ fragments: tile T = e*4+g covers expert e,
    // output cols c = g*16 + sub. B-operand element j holds W~[k][c]. ----
#if USE_K16
    h4 wf[16];
#pragma unroll
    for (int e = 0; e < 4; ++e)
#pragma unroll
        for (int g = 0; g < 4; ++g) {
            h4 f;
#pragma unroll
            for (int j = 0; j < 4; ++j) {
                const int k = quad * 4 + j;
                const int c = g * 16 + sub;
                float v = 0.0f;
                if (k < 14)       v = W[(e * 14 + k) * 64 + c];
                else if (k == 14) v = BIAS[e * 64 + c];
                f[j] = (_Float16)v;
            }
            wf[e * 4 + g] = f;
        }
#else
    h8 wf[16];   // k = 8*quad + j (quads 2,3 all zero)
#pragma unroll
    for (int e = 0; e < 4; ++e)
#pragma unroll
        for (int g = 0; g < 4; ++g) {
            h8 f;
#pragma unroll
            for (int j = 0; j < 8; ++j) {
                const int k = quad * 8 + j;
                const int c = g * 16 + sub;
                float v = 0.0f;
                if (k < 14)       v = W[(e * 14 + k) * 64 + c];
                else if (k == 14) v = BIAS[e * 64 + c];
                f[j] = (_Float16)v;
            }
            wf[e * 4 + g] = f;
        }
#endif

    float lsum = 0.0f;

    for (int t = wave; t < N_TILES; t += nwaves) {
        const int base = t * 16;

        // ids for my C/D rows (quad*4 + r), broadcast across the 16 sub-lanes
        const int4 ia = *(const int4*)(IDA + base + quad * 4);
        const int4 ib = *(const int4*)(IDB + base + quad * 4);
        const int* iap = (const int*)&ia;
        const int* ibp = (const int*)&ib;

        // A/B data fragments straight from global: my row = base + sub
        const float2* ra = (const float2*)(A + (size_t)(base + sub) * 14);
        const float2* rb = (const float2*)(B + (size_t)(base + sub) * 14);
#if USE_K16
        // k = 4*quad + j; quad 3: k12,k13 from memory, k14=1.0, k15=0
        float2 a0 = ra[2 * quad];
        float2 b0 = rb[2 * quad];
        float2 a1 = (quad < 3) ? ra[2 * quad + 1] : make_float2(1.0f, 0.0f);
        float2 b1 = (quad < 3) ? rb[2 * quad + 1] : make_float2(1.0f, 0.0f);
        h4 af, bf;
        af[0] = (_Float16)a0.x; af[1] = (_Float16)a0.y;
        af[2] = (_Float16)a1.x; af[3] = (_Float16)a1.y;
        bf[0] = (_Float16)b0.x; bf[1] = (_Float16)b0.y;
        bf[2] = (_Float16)b1.x; bf[3] = (_Float16)b1.y;
#else
        // k = 8*quad + j; quad0: k0..7, quad1: k8..13 + 1.0 + 0, quads 2,3: zero
        float2 a0 = {0,0}, a1 = {0,0}, a2 = {0,0}, a3 = {0,0};
        float2 b0 = {0,0}, b1 = {0,0}, b2 = {0,0}, b3 = {0,0};
        if (quad == 0) {
            a0 = ra[0]; a1 = ra[1]; a2 = ra[2]; a3 = ra[3];
            b0 = rb[0]; b1 = rb[1]; b2 = rb[2]; b3 = rb[3];
        } else if (quad == 1) {
            a0 = ra[4]; a1 = ra[5]; a2 = ra[6]; a3 = make_float2(1.0f, 0.0f);
            b0 = rb[4]; b1 = rb[5]; b2 = rb[6]; b3 = make_float2(1.0f, 0.0f);
        }
        h8 af, bf;
        af[0] = (_Float16)a0.x; af[1] = (_Float16)a0.y;
        af[2] = (_Float16)a1.x; af[3] = (_Float16)a1.y;
        af[4] = (_Float16)a2.x; af[5] = (_Float16)a2.y;
        af[6] = (_Float16)a3.x; af[7] = (_Float16)a3.y;
        bf[0] = (_Float16)b0.x; bf[1] = (_Float16)b0.y;
        bf[2] = (_Float16)b1.x; bf[3] = (_Float16)b1.y;
        bf[4] = (_Float16)b2.x; bf[5] = (_Float16)b2.y;
        bf[6] = (_Float16)b3.x; bf[7] = (_Float16)b3.y;
#endif

#pragma unroll
        for (int g = 0; g < 4; ++g) {
            f4 aA[4], aB[4];
            const f4 z = {0.0f, 0.0f, 0.0f, 0.0f};
#pragma unroll
            for (int e = 0; e < 4; ++e) {
#if USE_K16
                aA[e] = __builtin_amdgcn_mfma_f32_16x16x16f16(af, wf[e * 4 + g], z, 0, 0, 0);
                aB[e] = __builtin_amdgcn_mfma_f32_16x16x16f16(bf, wf[e * 4 + g], z, 0, 0, 0);
#else
                aA[e] = __builtin_amdgcn_mfma_f32_16x16x32_f16(af, wf[e * 4 + g], z, 0, 0, 0);
                aB[e] = __builtin_amdgcn_mfma_f32_16x16x32_f16(bf, wf[e * 4 + g], z, 0, 0, 0);
#endif
            }
            // C/D: my value r corresponds to data-row quad*4 + r, W-col g*16+sub.
#pragma unroll
            for (int r = 0; r < 4; ++r) {
                const int ja = iap[r];
                const int jb = ibp[r];
                float s0 = (ja & 1) ? aA[1][r] : aA[0][r];
                float s1 = (ja & 1) ? aA[3][r] : aA[2][r];
                float va = (ja & 2) ? s1 : s0;
                float t0 = (jb & 1) ? aB[1][r] : aB[0][r];
                float t1 = (jb & 1) ? aB[3][r] : aB[2][r];
                float vb = (jb & 2) ? t1 : t0;
                float d = va - vb;
                lsum = fmaf(d, d, lsum);
            }
        }
    }

    // wave reduction, one atomic per wave (pre-scaled -> mean over N*64)
#pragma unroll
    for (int off = 32; off > 0; off >>= 1)
        lsum += __shfl_down(lsum, off, 64);
    if (lane == 0)
        atomicAdd(out, lsum * (1.0f / 128000000.0f));
}

extern "C" void kernel_launch(void* const* d_in, const int* in_sizes, int n_in,
                              void* d_out, int out_size, void* d_ws, size_t ws_size,
                              hipStream_t stream) {
    const float* A    = (const float*)d_in[0];
    const float* B    = (const float*)d_in[1];
    const int*   IDA  = (const int*)d_in[2];
    const int*   IDB  = (const int*)d_in[3];
    const float* W    = (const float*)d_in[4];
    const float* BIAS = (const float*)d_in[5];
    float* out = (float*)d_out;

    hipMemsetAsync(out, 0, sizeof(float), stream);
    frame_loss<<<dim3(2048), dim3(256), 0, stream>>>(A, B, IDA, IDB, W, BIAS, out);
}